// Round 3
// baseline (325.050 us; speedup 1.0000x reference)
//
#include <hip/hip_runtime.h>

// out = a*residual + b*sublayer, (a,b) = column sums of 50-iter Sinkhorn on a
// 2x2 matrix. Memory-bound streaming kernel (~402 MB logical traffic).
//
// R3 design:
//  - grid-stride persistent blocks (2048 = exactly fills 8192 wave slots)
//  - BATCH=4 f4-pairs per iteration in NAMED registers, 8 loads (4 KB/wave)
//    in flight; __launch_bounds__(256,8) caps VGPR at 64 which FITS the
//    batch, so the allocator can't serialize it back down (R2 failure mode).
//  - 32-bit chunk indices (n4 = 8.4M fits int) to cut address VALU.
//  - Sinkhorn: all lanes redundantly, wave-uniform, recip-mul form (R2
//    bit-matched XLA, absmax 0.0). No LDS, no barrier.
//  - nontemporal stores: output is never re-read; don't evict the
//    L3-resident half of the inputs.

typedef float f4 __attribute__((ext_vector_type(4)));

#define SK_ITERS 50
constexpr int BLOCK = 256;
constexpr int BATCH = 4;                  // f4 chunks per thread per iter
constexpr int SPAN  = BLOCK * BATCH;      // 1024 chunks per block-iter

__global__ __launch_bounds__(BLOCK, 8) void sinkhorn_mix_kernel(
    const f4* __restrict__ r4, const f4* __restrict__ s4, f4* __restrict__ o4,
    const float* __restrict__ W_raw,
    const float* __restrict__ rs, const float* __restrict__ ss,
    float* __restrict__ os,
    int n4, long long n)
{
    const int tid = threadIdx.x;

    // ---- Sinkhorn 2x2 (uniform across all lanes; recip-mul form == XLA) ----
    const f4 w = *reinterpret_cast<const f4*>(W_raw);
    float w00 = fabsf(w.x) + 1e-8f;
    float w01 = fabsf(w.y) + 1e-8f;
    float w10 = fabsf(w.z) + 1e-8f;
    float w11 = fabsf(w.w) + 1e-8f;
    #pragma unroll 1
    for (int i = 0; i < SK_ITERS; ++i) {
        float t0 = 1.0f / (w00 + w01);   // row-normalize
        float t1 = 1.0f / (w10 + w11);
        w00 *= t0; w01 *= t0; w10 *= t1; w11 *= t1;
        float u0 = 1.0f / (w00 + w10);   // col-normalize
        float u1 = 1.0f / (w01 + w11);
        w00 *= u0; w10 *= u0; w01 *= u1; w11 *= u1;
    }
    const float a = w00 + w10;
    const float b = w01 + w11;

    const int stride = (int)gridDim.x * SPAN;

    for (int base = (int)blockIdx.x * SPAN + tid; base < n4; base += stride) {
        if (base + 3 * BLOCK < n4) {
            // ---- fast path: 8 loads issued back-to-back (4 KB in flight) ----
            f4 r0 = r4[base];
            f4 r1 = r4[base +     BLOCK];
            f4 r2 = r4[base + 2 * BLOCK];
            f4 r3 = r4[base + 3 * BLOCK];
            f4 s0 = s4[base];
            f4 s1 = s4[base +     BLOCK];
            f4 s2 = s4[base + 2 * BLOCK];
            f4 s3 = s4[base + 3 * BLOCK];

            f4 o0, o1, o2, o3;
            o0.x = a * r0.x + b * s0.x; o0.y = a * r0.y + b * s0.y;
            o0.z = a * r0.z + b * s0.z; o0.w = a * r0.w + b * s0.w;
            o1.x = a * r1.x + b * s1.x; o1.y = a * r1.y + b * s1.y;
            o1.z = a * r1.z + b * s1.z; o1.w = a * r1.w + b * s1.w;
            o2.x = a * r2.x + b * s2.x; o2.y = a * r2.y + b * s2.y;
            o2.z = a * r2.z + b * s2.z; o2.w = a * r2.w + b * s2.w;
            o3.x = a * r3.x + b * s3.x; o3.y = a * r3.y + b * s3.y;
            o3.z = a * r3.z + b * s3.z; o3.w = a * r3.w + b * s3.w;

            __builtin_nontemporal_store(o0, &o4[base]);
            __builtin_nontemporal_store(o1, &o4[base +     BLOCK]);
            __builtin_nontemporal_store(o2, &o4[base + 2 * BLOCK]);
            __builtin_nontemporal_store(o3, &o4[base + 3 * BLOCK]);
        } else {
            // ---- guarded tail: per-chunk bounds check ----
            #pragma unroll
            for (int k = 0; k < BATCH; ++k) {
                int i = base + k * BLOCK;
                if (i < n4) {
                    f4 rv = r4[i], sv = s4[i];
                    f4 ov;
                    ov.x = a * rv.x + b * sv.x;
                    ov.y = a * rv.y + b * sv.y;
                    ov.z = a * rv.z + b * sv.z;
                    ov.w = a * rv.w + b * sv.w;
                    __builtin_nontemporal_store(ov, &o4[i]);
                }
            }
        }
    }

    // scalar remainder for n % 4 != 0 (no-op at this problem size)
    if (blockIdx.x == 0) {
        for (long long e = 4LL * n4 + tid; e < n; e += BLOCK) {
            os[e] = a * rs[e] + b * ss[e];
        }
    }
}

extern "C" void kernel_launch(void* const* d_in, const int* in_sizes, int n_in,
                              void* d_out, int out_size, void* d_ws, size_t ws_size,
                              hipStream_t stream) {
    const float* residual = (const float*)d_in[0];
    const float* sublayer = (const float*)d_in[1];
    const float* W_raw    = (const float*)d_in[2];
    float* out            = (float*)d_out;

    const long long n  = (long long)out_size;     // 33,554,432
    const int       n4 = (int)(n >> 2);           // 8,388,608 f4 chunks

    long long needed = ((long long)n4 + SPAN - 1) / SPAN;
    int grid = (int)((needed < 2048) ? (needed < 1 ? 1 : needed) : 2048);

    sinkhorn_mix_kernel<<<grid, BLOCK, 0, stream>>>(
        (const f4*)residual, (const f4*)sublayer, (f4*)out, W_raw,
        residual, sublayer, out, n4, n);
}